// Round 7
// baseline (410.742 us; speedup 1.0000x reference)
//
#include <hip/hip_runtime.h>
#include <math.h>

// ---- problem constants (from reference setup_inputs) ----
constexpr int kNB   = 8;
constexpr int kNT   = 5;
constexpr int kNA   = 2;
constexpr int kNDET = 2;
constexpr int kNREG = 6;
constexpr int kNH   = 320;
constexpr int kNW   = 320;
constexpr int kHW   = kNH * kNW;          // 102400
constexpr int kHW4  = kHW / 4;            // 25600 float4-quads per plane
constexpr int kDetCh = kNA * kNDET * kNT; // 20 channels
constexpr int kRegCh = kNA * kNREG * kNT; // 60 channels
constexpr int kBoxFloats = kNB * kNT * kNA * kHW * 6; // 49,152,000
constexpr int kQuads = kNB * kNT * kHW4;  // 1,024,000 (one thread per 4 positions)
constexpr int kBlock = 256;
constexpr int kGrid  = kQuads / kBlock;   // 4000 (kHW4 % kBlock == 0: no plane straddle)

typedef float f32x4 __attribute__((ext_vector_type(4)));

__device__ __forceinline__ float sigmoidf_(float x) {
    return 1.0f / (1.0f + expf(-x));
}

__global__ __launch_bounds__(256) void fafe_predict(
    const float* __restrict__ det, const float* __restrict__ reg,
    float* __restrict__ out)
{
    // Per-WAVE 6 KB SoA regions (4 waves x 384 float4 = 24 KB total).
    // A wave transposes only its own 64 quads -> no __syncthreads anywhere:
    // within a wave, lanes run in lockstep and the compiler orders LDS
    // write->read with lgkmcnt. Waves proceed fully independently.
    __shared__ f32x4 lds4[4][6 * 64];

    const int tid  = threadIdx.x;
    const int wave = tid >> 6;
    const int lane = tid & 63;
    f32x4* wreg  = lds4[wave];
    float* wregf = reinterpret_cast<float*>(wreg);

    const int idx = blockIdx.x * kBlock + tid;   // quad id
    const int q   = idx % kHW4;                  // quad within (b,t) plane
    const int bt  = idx / kHW4;
    const int t   = bt % kNT;
    const int b   = bt / kNT;
    const int wb  = (q * 4) % kNW;               // w of first elem (320 % 4 == 0)
    const int wq  = q - lane;                    // wave's first quad in plane

    const float4* det4 = reinterpret_cast<const float4*>(det);
    const float4* reg4 = reinterpret_cast<const float4*>(reg);
    float4* out4 = reinterpret_cast<float4*>(out);

    constexpr int kPlane6o4  = kHW * 6 / 4;      // 153600 float4 per (bt,a) box plane
    constexpr int kMaskBase4 = kBoxFloats / 4;   // float4 offset of mask region

    // ---------------- issue ALL global loads upfront (16 in flight) ----------------
    // det channel = a*NDET*NT + c*NT + t = a*10 + c*5 + t
    const int dbase = (b * kDetCh + t) * kHW4 + q;
    const float4 d00 = det4[dbase + 0  * kHW4];  // a=0,c=0
    const float4 d01 = det4[dbase + 5  * kHW4];  // a=0,c=1
    const float4 d10 = det4[dbase + 10 * kHW4];  // a=1,c=0
    const float4 d11 = det4[dbase + 15 * kHW4];  // a=1,c=1

    // reg channel = a*NREG*NT + r*NT + t = a*30 + r*5 + t
    const int rbase = (b * kRegCh + t) * kHW4 + q;
    const float4 r00 = reg4[rbase + 0  * kHW4];
    const float4 r01 = reg4[rbase + 5  * kHW4];
    const float4 r02 = reg4[rbase + 10 * kHW4];
    const float4 r03 = reg4[rbase + 15 * kHW4];
    const float4 r04 = reg4[rbase + 20 * kHW4];
    const float4 r05 = reg4[rbase + 25 * kHW4];
    const float4 r10 = reg4[rbase + 30 * kHW4];
    const float4 r11 = reg4[rbase + 35 * kHW4];
    const float4 r12 = reg4[rbase + 40 * kHW4];
    const float4 r13 = reg4[rbase + 45 * kHW4];
    const float4 r14 = reg4[rbase + 50 * kHW4];
    const float4 r15 = reg4[rbase + 55 * kHW4];

    // ---------------- masks ----------------
    float p0[4], p1[4];
    f32x4 m0v, m1v;
    {
        const float* x00 = reinterpret_cast<const float*>(&d00);
        const float* x01 = reinterpret_cast<const float*>(&d01);
        const float* x10 = reinterpret_cast<const float*>(&d10);
        const float* x11 = reinterpret_cast<const float*>(&d11);
#pragma unroll
        for (int j = 0; j < 4; ++j) {
            // 2-class softmax channel 1 == sigmoid(x1 - x0)
            p0[j] = sigmoidf_(x01[j] - x00[j]);
            p1[j] = sigmoidf_(x11[j] - x10[j]);
            const bool best1 = p1[j] > p0[j];    // argmax, ties -> anchor 0
            m0v[j] = (p0[j] > 0.7f && !best1) ? 1.0f : 0.0f;
            m1v[j] = (p1[j] > 0.7f && best1) ? 1.0f : 0.0f;
        }
    }
    __builtin_nontemporal_store(
        m0v, reinterpret_cast<f32x4*>(&out4[kMaskBase4 + (bt * 2 + 0) * kHW4 + q]));
    __builtin_nontemporal_store(
        m1v, reinterpret_cast<f32x4*>(&out4[kMaskBase4 + (bt * 2 + 1) * kHW4 + q]));

    // ---------------- boxes: per-anchor wave-private transposed stores ----------------
#pragma unroll
    for (int a = 0; a < kNA; ++a) {
        const float4& r0 = (a == 0) ? r00 : r10;
        const float4& r1 = (a == 0) ? r01 : r11;
        const float4& r2 = (a == 0) ? r02 : r12;
        const float4& r3 = (a == 0) ? r03 : r13;
        const float4& r4 = (a == 0) ? r04 : r14;
        const float4& r5 = (a == 0) ? r05 : r15;
        const float a_l = (a == 0) ? 3.9f : 1.0f;
        const float a_w = (a == 0) ? 1.6f : 0.6f;
        const float* pp = (a == 0) ? p0 : p1;

        const float* x0 = reinterpret_cast<const float*>(&r0);
        const float* x1 = reinterpret_cast<const float*>(&r1);
        const float* x2 = reinterpret_cast<const float*>(&r2);
        const float* x3 = reinterpret_cast<const float*>(&r3);
        const float* x4 = reinterpret_cast<const float*>(&r4);
        const float* x5 = reinterpret_cast<const float*>(&r5);

        f32x4 cx, cy, cl, cw, cg, cs;   // per-component vectors over j=0..3
#pragma unroll
        for (int j = 0; j < 4; ++j) {
            const float gw  = (float)(wb + j);   // grid_x = w * 0.2f
            const float gwm = gw - 160.0f;       // grid_y = (w-160) * 0.2f
            cx[j] = sigmoidf_(x0[j]) * 0.2f + gw  * 0.2f;
            cy[j] = sigmoidf_(x1[j]) * 0.2f + gwm * 0.2f;
            cl[j] = expf(x3[j]) * a_l;           // l from t_l = reg[...,3]
            cw[j] = expf(x2[j]) * a_w;           // w from t_w = reg[...,2]
            cg[j] = atan2f(x5[j], x4[j]);
            cs[j] = pp[j];
        }

        // SoA write into the wave's region: comp c, positions lane*4..lane*4+3
        // -> float4 index c*64 + lane (bank-spread, lane-contiguous b128).
        wreg[0 * 64 + lane] = cx;
        wreg[1 * 64 + lane] = cy;
        wreg[2 * 64 + lane] = cl;
        wreg[3 * 64 + lane] = cw;
        wreg[4 * 64 + lane] = cg;
        wreg[5 * 64 + lane] = cs;
        __builtin_amdgcn_wave_barrier();  // scheduling fence only (no HW cost)

        // AoS gather + coalesced store: wave covers 384 float4 = its 64 quads.
        const int obase = (bt * 2 + a) * kPlane6o4 + wq * 6;
#pragma unroll
        for (int k = 0; k < 6; ++k) {
            const int o  = k * 64 + lane;        // float4 index within wave region
            const int f0 = 4 * o;                // first AoS float index
            f32x4 v;
#pragma unroll
            for (int e = 0; e < 4; ++e) {
                const int f = f0 + e;            // f = pos*6 + comp
                v[e] = wregf[(f % 6) * 256 + (f / 6)];
            }
            __builtin_nontemporal_store(
                v, reinterpret_cast<f32x4*>(&out4[obase + o]));
        }
        __builtin_amdgcn_wave_barrier();  // keep next anchor's writes after reads
    }
}

extern "C" void kernel_launch(void* const* d_in, const int* in_sizes, int n_in,
                              void* d_out, int out_size, void* d_ws, size_t ws_size,
                              hipStream_t stream) {
    const float* det = (const float*)d_in[0];
    const float* reg = (const float*)d_in[1];
    float* out = (float*)d_out;
    fafe_predict<<<kGrid, kBlock, 0, stream>>>(det, reg, out);
}